// Round 4
// baseline (264.158 us; speedup 1.0000x reference)
//
#include <hip/hip_runtime.h>
#include <hip/hip_bf16.h>
#include <math.h>

#define NB 256
#define SS 512
#define LL 128

typedef short bf16x8 __attribute__((ext_vector_type(8)));
typedef float f32x4 __attribute__((ext_vector_type(4)));

template <int P>
__device__ __forceinline__ float swzf(float x) {
    return __int_as_float(__builtin_amdgcn_ds_swizzle(__float_as_int(x), P));
}
__device__ __forceinline__ short f2bf(float f) {
    __hip_bfloat16 h = __float2bfloat16(f);
    short s;
    __builtin_memcpy(&s, &h, 2);
    return s;
}

// One block (128 thr = 2 waves) per batch. Wave 0 = forward chain, wave 1 =
// backward chain. Each wave runs its ENTIRE 128-wide recursion alone:
//   publish u image (2 ds_write_b16/lane) -> read 4 A-frags (broadcast
//   ds_read_b128, same-wave in-order DS, lgkmcnt only, NO barrier) ->
//   32 MFMAs (8 N-tiles x 4 K-frags, all-rows-equal A trick) -> exp/mask.
// exp(trans) fragments live in 128 VGPRs per wave. Features are register-
// prefetched 2 rounds ahead straight from global (no barriers -> no vmcnt
// drain). Exact power-of-2 rescale every 8 rounds, wave-local.
// The waves meet at ONE final barrier; block computes dot + loss, one
// atomicAdd per batch. Single kernel, no workspace.
__global__ __launch_bounds__(128, 1) void crf_kernel(
    const float* __restrict__ feats,    // (B,S,L)
    const float* __restrict__ start_t,  // (L)
    const float* __restrict__ end_t,    // (L)
    const float* __restrict__ trans,    // (L,L)
    const float* __restrict__ conf,     // (B)
    const int* __restrict__ mask,       // (B,S)
    const int* __restrict__ labels,     // (B,S)
    float* __restrict__ out)            // scalar, pre-zeroed
{
    const int b = blockIdx.x;
    const int tid = threadIdx.x;
    const int isB = tid >> 6;   // 0 = fwd wave, 1 = bwd wave
    const int l = tid & 63;
    const int l15 = l & 15;
    const int g = l >> 4;       // k-quad

    __shared__ __align__(16) short img[2][LL];  // u image per wave, bf16
    __shared__ int lmask[SS];
    __shared__ float sv[2][LL];                 // final alpha/beta, fp32
    __shared__ float sc[4];                     // eF, eB, lognum

    // stage masks once (single startup barrier; no loop barriers after)
#pragma unroll
    for (int q = 0; q < 4; ++q)
        lmask[tid + 128 * q] = mask[b * SS + tid + 128 * q];
    __syncthreads();

    const float* fb = feats + (size_t)b * SS * LL;

    // ---- exp(transition) B-fragments: Bf[kt][nt], 32 frags = 128 VGPRs ----
    // fwd: B[k][n] = exp(T[k][n]); bwd: exp(T[n][k]) (= T^T)
    bf16x8 Bf[4][8];
#pragma unroll
    for (int kt = 0; kt < 4; ++kt) {
#pragma unroll
        for (int nt = 0; nt < 8; ++nt) {
            const int n = 16 * nt + l15;
            bf16x8 fr;
#pragma unroll
            for (int j = 0; j < 8; ++j) {
                const int k = 32 * kt + 8 * g + j;
                const float v = isB ? trans[n * LL + k] : trans[k * LL + n];
                fr[j] = f2bf(__expf(v));
            }
            Bf[kt][nt] = fr;
        }
    }

    // ---- chain state: x[nt] = u[16*nt + l15], duplicated across g ----
    float x[8];
#pragma unroll
    for (int nt = 0; nt < 8; ++nt) {
        const int n = 16 * nt + l15;
        x[nt] = isB ? __expf(end_t[n]) : __expf(start_t[n] + fb[n]);
    }
    int eacc = 0;

    // round r processes t = r+1 (fwd) or 511-r (bwd)
    auto tof = [&](int r) { return isB ? (511 - r) : (r + 1); };

    // feature + mask prefetch, depth 2
    float fp[2][8];
    int mp[2];
#pragma unroll
    for (int h = 0; h < 2; ++h) {
        const float* rowp = fb + (size_t)tof(h) * LL;
#pragma unroll
        for (int nt = 0; nt < 8; ++nt) fp[h][nt] = rowp[16 * nt + l15];
        mp[h] = lmask[tof(h)];
    }

    short* const myimg = img[isB];

    for (int rp = 0; rp < 128; ++rp) {
#pragma unroll
        for (int h = 0; h < 2; ++h) {
            const int r = 2 * rp + h;
            float ft[8];
#pragma unroll
            for (int nt = 0; nt < 8; ++nt) ft[nt] = fp[h][nt];
            int mt = mp[h];
            if (r == 255 && !isB) mt = 0;  // fwd dummy round: keep alpha_255

            // prefetch round r+2
            if (rp < 127) {
                const float* rowp = fb + (size_t)tof(r + 2) * LL;
#pragma unroll
                for (int nt = 0; nt < 8; ++nt)
                    fp[h][nt] = rowp[16 * nt + l15];
                mp[h] = lmask[tof(r + 2)];
            }

            // publish u image: quad g writes N-tiles 2g, 2g+1
#pragma unroll
            for (int gg = 0; gg < 2; ++gg) {
                const int nt = 2 * g + gg;
                const float pub = isB ? __expf(ft[nt]) * x[nt] : x[nt];
                myimg[16 * nt + l15] = f2bf(pub);
            }

            // read A-frags (same-wave DS in-order; compiler inserts lgkmcnt)
            bf16x8 a[4];
#pragma unroll
            for (int kt = 0; kt < 4; ++kt)
                __builtin_memcpy(&a[kt], &myimg[32 * kt + 8 * g], 16);

            // 32 MFMAs: 8 independent accumulators, 4-deep K chains
            f32x4 c[8];
#pragma unroll
            for (int nt = 0; nt < 8; ++nt) {
                f32x4 cc = {0.f, 0.f, 0.f, 0.f};
                cc = __builtin_amdgcn_mfma_f32_16x16x32_bf16(a[0], Bf[0][nt], cc, 0, 0, 0);
                cc = __builtin_amdgcn_mfma_f32_16x16x32_bf16(a[1], Bf[1][nt], cc, 0, 0, 0);
                cc = __builtin_amdgcn_mfma_f32_16x16x32_bf16(a[2], Bf[2][nt], cc, 0, 0, 0);
                cc = __builtin_amdgcn_mfma_f32_16x16x32_bf16(a[3], Bf[3][nt], cc, 0, 0, 0);
                c[nt] = cc;
            }

            // all C rows equal: c[nt][0] = (u*E)[16*nt + l15]
#pragma unroll
            for (int nt = 0; nt < 8; ++nt) {
                const float cand = isB ? c[nt][0] : __expf(ft[nt]) * c[nt][0];
                x[nt] = mt ? cand : x[nt];
            }

            if ((r & 7) == 7) {
                // wave-local exact rescale: sum is bitwise-identical on all
                // lanes (g-duplicates), so ldexp keeps lanes consistent
                float s = 0.f;
#pragma unroll
                for (int nt = 0; nt < 8; ++nt) s += x[nt];
                s += swzf<0x041F>(s);  // xor 1
                s += swzf<0x081F>(s);  // xor 2
                s += swzf<0x101F>(s);  // xor 4
                s += swzf<0x201F>(s);  // xor 8
                int ex;
                frexpf(s, &ex);
#pragma unroll
                for (int nt = 0; nt < 8; ++nt) x[nt] = ldexpf(x[nt], -ex);
                eacc += ex;
            }
        }
    }

    // ---- export final vectors (fp32) + exponents to LDS ----
    if (g == 0) {
#pragma unroll
        for (int nt = 0; nt < 8; ++nt) sv[isB][16 * nt + l15] = x[nt];
    }
    if (l == 0) sc[isB] = (float)eacc;

    // ---- numerator (gold path, fp32 exact) on the bwd wave ----
    if (isB) {
        const int* lb = labels + b * SS;
        float term = 0.f;
        int cnt = 0;
#pragma unroll
        for (int rr = 0; rr < 8; ++rr) {
            const int tt = l + 64 * rr;
            int lc = lb[tt];
            if ((unsigned)lc >= LL) lc = 0;
            const int m = lmask[tt];
            cnt += (m != 0);
            if (tt == 0) {
                term += start_t[lc] + fb[lc];
            } else if (m) {
                int lp = lb[tt - 1];
                if ((unsigned)lp >= LL) lp = 0;
                term += trans[lp * LL + lc] + fb[(size_t)tt * LL + lc];
            }
        }
#pragma unroll
        for (int o = 1; o < 64; o <<= 1) {
            term += __shfl_xor(term, o);
            cnt += __shfl_xor(cnt, o);
        }
        if (l == 0) {
            int sl = cnt - 1;
            sl = sl < 0 ? 0 : (sl >= SS ? SS - 1 : sl);
            int lt = lb[sl];
            if ((unsigned)lt >= LL) lt = 0;
            sc[2] = term + end_t[lt];
        }
    }

    __syncthreads();  // the only post-startup barrier

    // ---- combine: Z = sum_i alpha_255[i] * beta_255[i] * 2^(eF+eB) ----
    if (tid < 64) {
        float p = sv[0][l] * sv[1][l] + sv[0][l + 64] * sv[1][l + 64];
#pragma unroll
        for (int o = 1; o < 64; o <<= 1) p += __shfl_xor(p, o);
        if (l == 0) {
            const float logZ =
                logf(p) + 0.69314718055994531f * (sc[0] + sc[1]);
            const float loss = (logZ - sc[2]) * conf[b] * (1.0f / NB);
            atomicAdd(out, loss);
        }
    }
}

extern "C" void kernel_launch(void* const* d_in, const int* in_sizes, int n_in,
                              void* d_out, int out_size, void* d_ws, size_t ws_size,
                              hipStream_t stream) {
    const float* feats  = (const float*)d_in[0];
    const float* startt = (const float*)d_in[1];
    const float* endt   = (const float*)d_in[2];
    const float* trans  = (const float*)d_in[3];
    const float* conf   = (const float*)d_in[4];
    const int*   mask   = (const int*)d_in[5];
    const int*   labels = (const int*)d_in[6];
    float* out = (float*)d_out;

    hipMemsetAsync(d_out, 0, sizeof(float), stream);
    hipLaunchKernelGGL(crf_kernel, dim3(NB), dim3(128), 0, stream,
                       feats, startt, endt, trans, conf, mask, labels, out);
}